// Round 8
// baseline (21591.214 us; speedup 1.0000x reference)
//
#include <hip/hip_runtime.h>
#include <stdint.h>

typedef long long i64;
typedef __attribute__((ext_vector_type(8))) short bf16x8;
typedef __attribute__((ext_vector_type(4))) float f32x4;

#define SV 11
#define SE 17
#define ARITY 10
#define NHEDGE 32768
#define NNODE 65536
#define NTOTAL 100000

__device__ __forceinline__ float b2f(ushort u) {
  union { uint32_t i; float f; } v; v.i = (uint32_t)u << 16; return v.f;
}
__device__ __forceinline__ ushort f2b(float f) {
  union { float f; uint32_t i; } v; v.f = f;
  uint32_t u = v.i + 0x7fffu + ((v.i >> 16) & 1u);
  return (ushort)(u >> 16);
}
__device__ __forceinline__ uint pack2(float a, float b) {
  return (uint)f2b(a) | ((uint)f2b(b) << 16);
}
__device__ __forceinline__ void cvt8(uint4 v, float* f) {
  f[0] = b2f((ushort)(v.x & 0xffff)); f[1] = b2f((ushort)(v.x >> 16));
  f[2] = b2f((ushort)(v.y & 0xffff)); f[3] = b2f((ushort)(v.y >> 16));
  f[4] = b2f((ushort)(v.z & 0xffff)); f[5] = b2f((ushort)(v.z >> 16));
  f[6] = b2f((ushort)(v.w & 0xffff)); f[7] = b2f((ushort)(v.w >> 16));
}

__device__ __forceinline__ void gload_lds16(const void* g, void* l) {
  __builtin_amdgcn_global_load_lds((const __attribute__((address_space(1))) void*)g,
                                   (__attribute__((address_space(3))) void*)l, 16, 0, 0);
}

__device__ __forceinline__ int xcd_swizzle(int orig, int nwg) {
  const int xcd = orig & 7, rest = orig >> 3;
  const int q = nwg >> 3, r = nwg & 7;
  return (xcd < r ? xcd * (q + 1) : r * (q + 1) + (xcd - r) * q) + rest;
}

// ================= compaction: count / scan / fill =============================
__global__ __launch_bounds__(256) void cnt_k(const int* __restrict__ mask, int width,
                                             int extra, int* __restrict__ cnt, int n) {
  const int i = blockIdx.x * 256 + threadIdx.x;
  if (i >= n) return;
  int c = extra;
  for (int j = 0; j < width; j++) c += (mask[(i64)i * width + j] != 0);
  cnt[i] = c;
}

__global__ __launch_bounds__(256) void scan1_k(const int* __restrict__ cnt,
                                               int* __restrict__ ss,
                                               int* __restrict__ part, int n) {
  __shared__ int sm[256];
  const int i = blockIdx.x * 256 + threadIdx.x;
  const int v = (i < n) ? cnt[i] : 0;
  sm[threadIdx.x] = v;
  __syncthreads();
  for (int o = 1; o < 256; o <<= 1) {
    const int t = (threadIdx.x >= o) ? sm[threadIdx.x - o] : 0;
    __syncthreads();
    sm[threadIdx.x] += t;
    __syncthreads();
  }
  if (i < n) ss[i] = sm[threadIdx.x] - v;  // exclusive
  if (threadIdx.x == 255) part[blockIdx.x] = sm[255];
}

__global__ __launch_bounds__(256) void scan2_k(int* __restrict__ part, int nb,
                                               int* __restrict__ ss, int n) {
  __shared__ int sm[256];
  const int v = (threadIdx.x < nb) ? part[threadIdx.x] : 0;
  sm[threadIdx.x] = v;
  __syncthreads();
  for (int o = 1; o < 256; o <<= 1) {
    const int t = (threadIdx.x >= o) ? sm[threadIdx.x - o] : 0;
    __syncthreads();
    sm[threadIdx.x] += t;
    __syncthreads();
  }
  if (threadIdx.x < nb) part[threadIdx.x] = sm[threadIdx.x] - v;
  if (threadIdx.x == 255) ss[n] = sm[255];
}

__global__ __launch_bounds__(256) void scan3_k(int* __restrict__ ss,
                                               const int* __restrict__ part,
                                               const int* __restrict__ mask, int width,
                                               int extra, int* __restrict__ tok, int n) {
  const int i = blockIdx.x * 256 + threadIdx.x;
  if (i >= n) return;
  int off = ss[i] + part[blockIdx.x];
  ss[i] = off;
  if (extra) {
    tok[off++] = (i << 5);
    for (int j = 0; j < width; j++)
      if (mask[(i64)i * width + j] != 0) tok[off++] = (i << 5) | (j + 1);
  } else {
    for (int j = 0; j < width; j++)
      if (mask[(i64)i * width + j] != 0) tok[off++] = (i << 5) | j;
  }
}

// ============ 256x256 bf16 MFMA GEMM, double-buffered LDS ======================
// C[M,N] = act(A@W^T + bias). 8 waves (2r x 4c), BK=64, 1 barrier/K-step.
// LDS 128KB (2 bufs x (A 32KB + W 32KB)); stage(next) issued right after the
// barrier so it flies under ds_read+MFMA of cur and drains at the next barrier.
template <int K, int MODE>
__global__ __launch_bounds__(512, 1) void gemm256_k(const ushort* __restrict__ A,
                                                    const ushort* __restrict__ W,
                                                    const float* __restrict__ bias,
                                                    ushort* __restrict__ C, int M, int N,
                                                    const int* ssn, int nseq) {
  const int tid = threadIdx.x;
  const int wave = tid >> 6, lane = tid & 63;
  const int nwg = gridDim.x * gridDim.y;
  const int wg = xcd_swizzle(blockIdx.y * gridDim.x + blockIdx.x, nwg);
  const int bx = wg % gridDim.x, by = wg / gridDim.x;
  const int m0 = by << 8, n0 = bx << 8;
  if (ssn && m0 >= ssn[nseq] - ssn[0]) return;
  __shared__ ushort As[2][256 * 64];
  __shared__ ushort Ws[2][256 * 64];
  const int wr = wave >> 2, wc = wave & 3;

  f32x4 acc[8][4];
#pragma unroll
  for (int m = 0; m < 8; m++)
#pragma unroll
    for (int n = 0; n < 4; n++) acc[m][n] = (f32x4){0.f, 0.f, 0.f, 0.f};

  // staging: 2048 16B-units per matrix; thread's unit for call i: u = i*512+tid.
  // row = i*64 + wave*8 + (lane>>3); pre-swizzled kblk = (lane&7)^(lane>>3).
  const int kg = ((lane & 7) ^ (lane >> 3)) << 3;  // element offset
  const int rb = (wave << 3) + (lane >> 3);
  const ushort* Ag[4];
  const ushort* Wg[4];
#pragma unroll
  for (int i = 0; i < 4; i++) {
    Ag[i] = A + (i64)(m0 + (i << 6) + rb) * K + kg;
    Wg[i] = W + (i64)(n0 + (i << 6) + rb) * K + kg;
  }

#define STAGE256(buf, k0)                                              \
  {                                                                    \
    _Pragma("unroll") for (int i = 0; i < 4; i++) {                    \
      gload_lds16(Ag[i] + (k0), (char*)&As[buf][0] + (wave << 10) + (i << 13)); \
      gload_lds16(Wg[i] + (k0), (char*)&Ws[buf][0] + (wave << 10) + (i << 13)); \
    }                                                                  \
  }

  STAGE256(0, 0)
  const int T = K / 64;
  for (int t = 0; t < T; t++) {
    const int cur = t & 1;
    __syncthreads();  // drains own stage; all waves' prev reads done
    if (t + 1 < T) STAGE256(cur ^ 1, (t + 1) * 64)
#pragma unroll
    for (int kh = 0; kh < 2; kh++) {
      const int kb = (kh << 2) + (lane >> 4);
      bf16x8 af[8], bf[4];
#pragma unroll
      for (int m = 0; m < 8; m++) {
        const int row = (wr << 7) + (m << 4) + (lane & 15);
        af[m] = *(const bf16x8*)&As[cur][row * 64 + ((kb ^ (row & 7)) << 3)];
      }
#pragma unroll
      for (int n = 0; n < 4; n++) {
        const int row = (wc << 6) + (n << 4) + (lane & 15);
        bf[n] = *(const bf16x8*)&Ws[cur][row * 64 + ((kb ^ (row & 7)) << 3)];
      }
#pragma unroll
      for (int m = 0; m < 8; m++)
#pragma unroll
        for (int n = 0; n < 4; n++)
          acc[m][n] = __builtin_amdgcn_mfma_f32_16x16x32_bf16(bf[n], af[m], acc[m][n], 0, 0, 0);
    }
  }
#undef STAGE256

#pragma unroll
  for (int m = 0; m < 8; m++) {
    const int row = m0 + (wr << 7) + (m << 4) + (lane & 15);
#pragma unroll
    for (int n = 0; n < 4; n++) {
      const int col = n0 + (wc << 6) + (n << 4) + ((lane >> 4) << 2);
      float v0 = acc[m][n][0], v1 = acc[m][n][1], v2 = acc[m][n][2], v3 = acc[m][n][3];
      if (MODE > 0) {
        const f32x4 bv = *(const f32x4*)&bias[col];
        v0 += bv[0]; v1 += bv[1]; v2 += bv[2]; v3 += bv[3];
      }
      if (MODE == 2) {
        v0 = fmaxf(v0, 0.f); v1 = fmaxf(v1, 0.f);
        v2 = fmaxf(v2, 0.f); v3 = fmaxf(v3, 0.f);
      }
      uint2 o; o.x = pack2(v0, v1); o.y = pack2(v2, v3);
      *(uint2*)&C[(i64)row * N + col] = o;
    }
  }
}

// ================= 128x128 bf16 MFMA GEMM (CLS path) ==========================
template <int K, int MODE>
__global__ __launch_bounds__(256) void gemm_bf16_k(const ushort* __restrict__ A,
                                                   const ushort* __restrict__ W,
                                                   const float* __restrict__ bias,
                                                   ushort* __restrict__ C, int M, int N,
                                                   const int* ssn, int nseq,
                                                   const int* arp) {
  const int tid = threadIdx.x;
  const int wave = tid >> 6, lane = tid & 63;
  const int nwg = gridDim.x * gridDim.y;
  const int wg = xcd_swizzle(blockIdx.y * gridDim.x + blockIdx.x, nwg);
  const int bx = wg % gridDim.x, by = wg / gridDim.x;
  const int m0 = by << 7, n0 = bx << 7;
  if (ssn && m0 >= ssn[nseq] - ssn[0]) return;
  __shared__ ushort As[128 * 64];
  __shared__ ushort Ws[128 * 64];
  const int wr = wave >> 1, wc = wave & 1;

  f32x4 acc[4][4];
#pragma unroll
  for (int m = 0; m < 4; m++)
#pragma unroll
    for (int n = 0; n < 4; n++) acc[m][n] = (f32x4){0.f, 0.f, 0.f, 0.f};

  const int srow = (wave << 5) + (lane >> 3);
  const int kblk_g = (lane & 7) ^ (lane >> 3);
  const i64 arow = arp ? (i64)(arp[m0 + srow] - arp[0]) : (i64)(m0 + srow);
  const ushort* Ag = A + arow * K + (kblk_g << 3);
  const ushort* Wg = W + (i64)(n0 + srow) * K + (kblk_g << 3);
  char* lA = (char*)As + (wave << 12);
  char* lB = (char*)Ws + (wave << 12);

#pragma unroll
  for (int i = 0; i < 4; i++) {
    gload_lds16(Ag + (i64)(i * 8) * K, lA + i * 1024);
    gload_lds16(Wg + (i64)(i * 8) * K, lB + i * 1024);
  }

  for (int k0 = 0; k0 < K; k0 += 64) {
    __syncthreads();
    bf16x8 af[2][4], bf[2][4];
#pragma unroll
    for (int kh = 0; kh < 2; kh++) {
      const int kb = (kh << 2) + (lane >> 4);
#pragma unroll
      for (int m = 0; m < 4; m++) {
        const int row = (wr << 6) + (m << 4) + (lane & 15);
        af[kh][m] = *(const bf16x8*)&As[row * 64 + ((kb ^ (row & 7)) << 3)];
      }
#pragma unroll
      for (int n = 0; n < 4; n++) {
        const int row = (wc << 6) + (n << 4) + (lane & 15);
        bf[kh][n] = *(const bf16x8*)&Ws[row * 64 + ((kb ^ (row & 7)) << 3)];
      }
    }
    __syncthreads();
    if (k0 + 64 < K) {
#pragma unroll
      for (int i = 0; i < 4; i++) {
        gload_lds16(Ag + (k0 + 64) + (i64)(i * 8) * K, lA + i * 1024);
        gload_lds16(Wg + (k0 + 64) + (i64)(i * 8) * K, lB + i * 1024);
      }
    }
#pragma unroll
    for (int kh = 0; kh < 2; kh++)
#pragma unroll
      for (int m = 0; m < 4; m++)
#pragma unroll
        for (int n = 0; n < 4; n++)
          acc[m][n] = __builtin_amdgcn_mfma_f32_16x16x32_bf16(bf[kh][n], af[kh][m], acc[m][n], 0, 0, 0);
  }

#pragma unroll
  for (int m = 0; m < 4; m++) {
    const int row = m0 + (wr << 6) + (m << 4) + (lane & 15);
#pragma unroll
    for (int n = 0; n < 4; n++) {
      const int col = n0 + (wc << 6) + (n << 4) + ((lane >> 4) << 2);
      float v0 = acc[m][n][0], v1 = acc[m][n][1], v2 = acc[m][n][2], v3 = acc[m][n][3];
      if (MODE > 0) {
        const f32x4 bv = *(const f32x4*)&bias[col];
        v0 += bv[0]; v1 += bv[1]; v2 += bv[2]; v3 += bv[3];
      }
      if (MODE == 2) {
        v0 = fmaxf(v0, 0.f); v1 = fmaxf(v1, 0.f);
        v2 = fmaxf(v2, 0.f); v3 = fmaxf(v3, 0.f);
      }
      uint2 o; o.x = pack2(v0, v1); o.y = pack2(v2, v3);
      *(uint2*)&C[(i64)row * N + col] = o;
    }
  }
}

// ============ Fused GEMM + residual + LayerNorm (N = 256) ======================
template <int K>
__global__ __launch_bounds__(512) void gemm_ln_k(const ushort* __restrict__ A,
                                                 const ushort* __restrict__ W,
                                                 const float* __restrict__ bias,
                                                 const ushort* R, int rstride,
                                                 const float* __restrict__ g,
                                                 const float* __restrict__ b,
                                                 ushort* C, int cstride, int M,
                                                 const int* ssn, int nseq,
                                                 const int* rrp) {
  const int m0 = blockIdx.x << 7;
  if (ssn && m0 >= ssn[nseq] - ssn[0]) return;
  __shared__ ushort As[128 * 64];
  __shared__ ushort Ws[256 * 64];
  __shared__ float partS[128][4];
  __shared__ float partQ[128][4];
  const int tid = threadIdx.x;
  const int wave = tid >> 6, lane = tid & 63;
  const int wr = wave >> 2, wc = wave & 3;

  f32x4 acc[4][4];
#pragma unroll
  for (int m = 0; m < 4; m++)
#pragma unroll
    for (int n = 0; n < 4; n++) acc[m][n] = (f32x4){0.f, 0.f, 0.f, 0.f};

  int rowA[2], kgA[2];
#pragma unroll
  for (int i = 0; i < 2; i++) {
    const int u = wave * 128 + i * 64 + lane;
    rowA[i] = u >> 3; kgA[i] = (u & 7) ^ ((u >> 3) & 7);
  }
  int rowW[4], kgW[4];
#pragma unroll
  for (int i = 0; i < 4; i++) {
    const int u = wave * 256 + i * 64 + lane;
    rowW[i] = u >> 3; kgW[i] = (u & 7) ^ ((u >> 3) & 7);
  }

#pragma unroll
  for (int i = 0; i < 2; i++)
    gload_lds16(A + (i64)(m0 + rowA[i]) * K + (kgA[i] << 3),
                (char*)As + (wave * 128 + i * 64) * 16);
#pragma unroll
  for (int i = 0; i < 4; i++)
    gload_lds16(W + (i64)rowW[i] * K + (kgW[i] << 3),
                (char*)Ws + (wave * 256 + i * 64) * 16);

  for (int k0 = 0; k0 < K; k0 += 64) {
    __syncthreads();
    bf16x8 af[2][4], bf[2][4];
#pragma unroll
    for (int kh = 0; kh < 2; kh++) {
      const int kb = (kh << 2) + (lane >> 4);
#pragma unroll
      for (int m = 0; m < 4; m++) {
        const int row = (wr << 6) + (m << 4) + (lane & 15);
        af[kh][m] = *(const bf16x8*)&As[row * 64 + ((kb ^ (row & 7)) << 3)];
      }
#pragma unroll
      for (int n = 0; n < 4; n++) {
        const int row = (wc << 6) + (n << 4) + (lane & 15);
        bf[kh][n] = *(const bf16x8*)&Ws[row * 64 + ((kb ^ (row & 7)) << 3)];
      }
    }
    __syncthreads();
    if (k0 + 64 < K) {
#pragma unroll
      for (int i = 0; i < 2; i++)
        gload_lds16(A + (i64)(m0 + rowA[i]) * K + (k0 + 64) + (kgA[i] << 3),
                    (char*)As + (wave * 128 + i * 64) * 16);
#pragma unroll
      for (int i = 0; i < 4; i++)
        gload_lds16(W + (i64)rowW[i] * K + (k0 + 64) + (kgW[i] << 3),
                    (char*)Ws + (wave * 256 + i * 64) * 16);
    }
#pragma unroll
    for (int kh = 0; kh < 2; kh++)
#pragma unroll
      for (int m = 0; m < 4; m++)
#pragma unroll
        for (int n = 0; n < 4; n++)
          acc[m][n] = __builtin_amdgcn_mfma_f32_16x16x32_bf16(bf[kh][n], af[kh][m], acc[m][n], 0, 0, 0);
  }

#pragma unroll
  for (int m = 0; m < 4; m++) {
    const int tokl = (wr << 6) + (m << 4) + (lane & 15);
    const int row = m0 + tokl;
    const i64 rr = rrp ? (i64)(rrp[row] - rrp[0]) : (i64)row;
    float s = 0.f, q = 0.f;
#pragma unroll
    for (int n = 0; n < 4; n++) {
      const int col = (wc << 6) + (n << 4) + ((lane >> 4) << 2);
      const f32x4 bv = *(const f32x4*)&bias[col];
      const uint2 ru = *(const uint2*)&R[rr * rstride + col];
      float v0 = acc[m][n][0] + bv[0] + b2f((ushort)(ru.x & 0xffff));
      float v1 = acc[m][n][1] + bv[1] + b2f((ushort)(ru.x >> 16));
      float v2 = acc[m][n][2] + bv[2] + b2f((ushort)(ru.y & 0xffff));
      float v3 = acc[m][n][3] + bv[3] + b2f((ushort)(ru.y >> 16));
      acc[m][n][0] = v0; acc[m][n][1] = v1; acc[m][n][2] = v2; acc[m][n][3] = v3;
      s += v0 + v1 + v2 + v3;
      q += v0 * v0 + v1 * v1 + v2 * v2 + v3 * v3;
    }
    s += __shfl_xor(s, 16, 64); s += __shfl_xor(s, 32, 64);
    q += __shfl_xor(q, 16, 64); q += __shfl_xor(q, 32, 64);
    if (lane < 16) { partS[tokl][wc] = s; partQ[tokl][wc] = q; }
  }
  __syncthreads();
#pragma unroll
  for (int m = 0; m < 4; m++) {
    const int tokl = (wr << 6) + (m << 4) + (lane & 15);
    const i64 row = (i64)(m0 + tokl);
    const f32x4 s4 = *(const f32x4*)&partS[tokl][0];
    const f32x4 q4 = *(const f32x4*)&partQ[tokl][0];
    const float mean = (s4[0] + s4[1] + s4[2] + s4[3]) * (1.f / 256.f);
    const float var = (q4[0] + q4[1] + q4[2] + q4[3]) * (1.f / 256.f) - mean * mean;
    const float rs = rsqrtf(var + 1e-5f);
#pragma unroll
    for (int n = 0; n < 4; n++) {
      const int col = (wc << 6) + (n << 4) + ((lane >> 4) << 2);
      const f32x4 g4 = *(const f32x4*)&g[col];
      const f32x4 b4 = *(const f32x4*)&b[col];
      uint2 o;
      o.x = pack2((acc[m][n][0] - mean) * rs * g4[0] + b4[0],
                  (acc[m][n][1] - mean) * rs * g4[1] + b4[1]);
      o.y = pack2((acc[m][n][2] - mean) * rs * g4[2] + b4[2],
                  (acc[m][n][3] - mean) * rs * g4[3] + b4[3]);
      *(uint2*)&C[row * cstride + col] = o;
    }
  }
}

// ========= Layer-1 attention (compact, mask-free, variable length) ============
template <int S>
__global__ __launch_bounds__(16 * S) void attn1_k(const ushort* __restrict__ QKV,
                                                  const int* __restrict__ ss,
                                                  ushort* __restrict__ O) {
  __shared__ float KL[4][S][68];
  __shared__ float VL[4][S][68];
  const int tid = threadIdx.x;
  const int s0 = ss[0];
  const int base = ss[blockIdx.x] - s0;
  const int L = ss[blockIdx.x + 1] - ss[blockIdx.x];

  for (int u = tid; u < 128 * L; u += 16 * S) {
    const int d4 = u & 15, h = (u >> 4) & 3, mt = u >> 6;
    const int mat = (mt >= L), t = mat ? mt - L : mt;
    const ushort* gp = QKV + (i64)(base + t) * 768 + 256 + mat * 256 + h * 64 + d4 * 4;
    ushort4 raw = *(const ushort4*)gp;
    float* dst = (mat ? &VL[h][t][0] : &KL[h][t][0]) + d4 * 4;
    dst[0] = b2f(raw.x); dst[1] = b2f(raw.y); dst[2] = b2f(raw.z); dst[3] = b2f(raw.w);
  }
  __syncthreads();

  const int h = tid / (4 * S);
  const int r = tid - h * 4 * S;
  const int q = r >> 2, j = r & 3;
  if (q >= L) return;

  float qv[16];
  {
    const ushort* qp = QKV + (i64)(base + q) * 768 + h * 64 + j * 16;
    cvt8(*(const uint4*)qp, qv);
    cvt8(*(const uint4*)(qp + 8), qv + 8);
  }

  float w[S];
  float mx = -1e30f;
#pragma unroll
  for (int s = 0; s < S; s++) {
    float p = -1e30f;
    if (s < L) {
      const float* kr = &KL[h][s][j * 16];
      p = 0.f;
#pragma unroll
      for (int e = 0; e < 4; e++) {
        const float4 kv = *(const float4*)(kr + e * 4);
        p = fmaf(qv[e * 4 + 0], kv.x, p);
        p = fmaf(qv[e * 4 + 1], kv.y, p);
        p = fmaf(qv[e * 4 + 2], kv.z, p);
        p = fmaf(qv[e * 4 + 3], kv.w, p);
      }
      p += __shfl_xor(p, 1, 64);
      p += __shfl_xor(p, 2, 64);
      p *= 0.125f;
    }
    w[s] = p;
    mx = fmaxf(mx, p);
  }
  float sum = 0.f;
#pragma unroll
  for (int s = 0; s < S; s++) { w[s] = __expf(w[s] - mx); sum += w[s]; }
  const float inv = 1.f / sum;

  float o[16];
#pragma unroll
  for (int e = 0; e < 16; e++) o[e] = 0.f;
#pragma unroll
  for (int s = 0; s < S; s++) {
    if (s < L) {
      const float ws = w[s];
      const float* vr = &VL[h][s][j * 16];
#pragma unroll
      for (int e = 0; e < 4; e++) {
        const float4 vv = *(const float4*)(vr + e * 4);
        o[e * 4 + 0] = fmaf(ws, vv.x, o[e * 4 + 0]);
        o[e * 4 + 1] = fmaf(ws, vv.y, o[e * 4 + 1]);
        o[e * 4 + 2] = fmaf(ws, vv.z, o[e * 4 + 2]);
        o[e * 4 + 3] = fmaf(ws, vv.w, o[e * 4 + 3]);
      }
    }
  }
  uint4 st0, st1;
  st0.x = pack2(o[0] * inv, o[1] * inv);   st0.y = pack2(o[2] * inv, o[3] * inv);
  st0.z = pack2(o[4] * inv, o[5] * inv);   st0.w = pack2(o[6] * inv, o[7] * inv);
  st1.x = pack2(o[8] * inv, o[9] * inv);   st1.y = pack2(o[10] * inv, o[11] * inv);
  st1.z = pack2(o[12] * inv, o[13] * inv); st1.w = pack2(o[14] * inv, o[15] * inv);
  ushort* op = O + (i64)(base + q) * 256 + h * 64 + j * 16;
  *(uint4*)op = st0;
  *(uint4*)(op + 8) = st1;
}

// ===== Layer-2 attention, CLS query ===========================================
template <int S>
__global__ __launch_bounds__(256) void attn_cls_k(const ushort* __restrict__ Qc,
                                                  const ushort* __restrict__ KV,
                                                  const int* __restrict__ ss,
                                                  ushort* __restrict__ Ocls) {
  const int tid = threadIdx.x;
  const int sl = tid >> 4, h = (tid >> 2) & 3, j = tid & 3;
  const int seq = blockIdx.x * 16 + sl;
  const int base = ss[seq] - ss[0];
  const int L = ss[seq + 1] - ss[seq];

  float qv[16];
  {
    const ushort* qp = Qc + (i64)seq * 256 + h * 64 + j * 16;
    cvt8(*(const uint4*)qp, qv);
    cvt8(*(const uint4*)(qp + 8), qv + 8);
  }
  float w[S];
  float mx = -1e30f;
#pragma unroll
  for (int s = 0; s < S; s++) {
    float p = -1e30f;
    if (s < L) {
      float kf[16];
      const ushort* kp = KV + (i64)(base + s) * 512 + h * 64 + j * 16;
      cvt8(*(const uint4*)kp, kf);
      cvt8(*(const uint4*)(kp + 8), kf + 8);
      p = 0.f;
#pragma unroll
      for (int e = 0; e < 16; e++) p = fmaf(qv[e], kf[e], p);
      p += __shfl_xor(p, 1, 64);
      p += __shfl_xor(p, 2, 64);
      p *= 0.125f;
    }
    w[s] = p;
    mx = fmaxf(mx, p);
  }
  float sum = 0.f;
#pragma unroll
  for (int s = 0; s < S; s++) { w[s] = __expf(w[s] - mx); sum += w[s]; }
  const float inv = 1.f / sum;

  float o[16];
#pragma unroll
  for (int e = 0; e < 16; e++) o[e] = 0.f;
#pragma unroll
  for (int s = 0; s < S; s++) {
    if (s < L) {
      float vf[16];
      const ushort* vp = KV + (i64)(base + s) * 512 + 256 + h * 64 + j * 16;
      cvt8(*(const uint4*)vp, vf);
      cvt8(*(const uint4*)(vp + 8), vf + 8);
      const float ws = w[s];
#pragma unroll
      for (int e = 0; e < 16; e++) o[e] = fmaf(ws, vf[e], o[e]);
    }
  }
  uint4 st0, st1;
  st0.x = pack2(o[0] * inv, o[1] * inv);   st0.y = pack2(o[2] * inv, o[3] * inv);
  st0.z = pack2(o[4] * inv, o[5] * inv);   st0.w = pack2(o[6] * inv, o[7] * inv);
  st1.x = pack2(o[8] * inv, o[9] * inv);   st1.y = pack2(o[10] * inv, o[11] * inv);
  st1.z = pack2(o[12] * inv, o[13] * inv); st1.w = pack2(o[14] * inv, o[15] * inv);
  ushort* op = Ocls + (i64)seq * 256 + h * 64 + j * 16;
  *(uint4*)op = st0;
  *(uint4*)(op + 8) = st1;
}

// ================= gathers / scatters / conversion =============================
__global__ __launch_bounds__(256) void f2b_cvt_k(const float* __restrict__ in,
                                                 ushort* __restrict__ out, int n) {
  for (int i = blockIdx.x * 256 + threadIdx.x; i < n; i += gridDim.x * 256)
    out[i] = f2b(in[i]);
}

__global__ __launch_bounds__(256) void gather_v2e_k(const float* __restrict__ unity,
                                                    const float* __restrict__ pos,
                                                    const int* __restrict__ xid,
                                                    const int* __restrict__ xpos,
                                                    const int* __restrict__ tok,
                                                    const int* __restrict__ ss, int nseq,
                                                    ushort* __restrict__ X) {
  const int t = blockIdx.x * 4 + (threadIdx.x >> 6);
  const int lane = threadIdx.x & 63;
  const int s0 = ss[0];
  if (t >= ss[nseq] - s0) return;
  const int code = tok[s0 + t];
  const int e = code >> 5, slot = code & 31;
  float4 v = make_float4(0.f, 0.f, 0.f, 0.f);
  if (slot > 0) {
    const int id = xid[(i64)e * ARITY + (slot - 1)];
    v = *(const float4*)&unity[(i64)id * 256 + lane * 4];
  }
  const int pp = xpos[(i64)e * SV + slot];
  const float4 pv = *(const float4*)&pos[(i64)pp * 256 + lane * 4];
  uint2 o;
  o.x = pack2(v.x + pv.x, v.y + pv.y);
  o.y = pack2(v.z + pv.z, v.w + pv.w);
  *(uint2*)&X[(i64)t * 256 + lane * 4] = o;
}

__global__ __launch_bounds__(256) void gather_e2v_k(const ushort* __restrict__ ext,
                                                    const int* __restrict__ hid,
                                                    const int* __restrict__ tok,
                                                    const int* __restrict__ ss, int nseq,
                                                    ushort* __restrict__ X) {
  const int t = blockIdx.x * 4 + (threadIdx.x >> 6);
  const int lane = threadIdx.x & 63;
  const int s0 = ss[0];
  if (t >= ss[nseq] - s0) return;
  const int code = tok[s0 + t];
  const int n = code >> 5, slot = code & 31;
  const int id = hid[(i64)n * SE + slot];
  *(uint2*)&X[(i64)t * 256 + lane * 4] =
      *(const uint2*)&ext[(i64)id * 256 + lane * 4];
}

__global__ __launch_bounds__(256) void scatter_k(const ushort* __restrict__ Xc,
                                                 const int* __restrict__ subg,
                                                 float* __restrict__ unity, int n0) {
  const int nl = blockIdx.x * 4 + (threadIdx.x >> 6);
  const int lane = threadIdx.x & 63;
  const int dst = subg[n0 + nl];
  ushort4 v = *(const ushort4*)&Xc[(i64)nl * 256 + lane * 4];
  float4 o; o.x = b2f(v.x); o.y = b2f(v.y); o.z = b2f(v.z); o.w = b2f(v.w);
  *(float4*)&unity[(i64)dst * 256 + lane * 4] = o;
}

__global__ __launch_bounds__(256) void ext_init_k(ushort* __restrict__ ext,
                                                  const float* __restrict__ pad,
                                                  const float* __restrict__ cls) {
  const int d = threadIdx.x;
  ext[(i64)NHEDGE * 256 + d] = f2b(pad[d]);
  ext[(i64)(NHEDGE + 1) * 256 + d] = f2b(cls[d]);
}

__global__ __launch_bounds__(256) void out_gather_k(const ushort* __restrict__ ext,
                                                    const int* __restrict__ pred,
                                                    float* __restrict__ out) {
  const int i = blockIdx.x * 4 + (threadIdx.x >> 6);
  const int lane = threadIdx.x & 63;
  const int e = pred[i];
  ushort4 v = *(const ushort4*)&ext[(i64)e * 256 + lane * 4];
  float4 o; o.x = b2f(v.x); o.y = b2f(v.y); o.z = b2f(v.z); o.w = b2f(v.w);
  *(float4*)&out[(i64)i * 256 + lane * 4] = o;
}

// ================= host orchestration ==========================================
extern "C" void kernel_launch(void* const* d_in, const int* in_sizes, int n_in,
                              void* d_out, int out_size, void* d_ws, size_t ws_size,
                              hipStream_t stream) {
  (void)in_sizes; (void)n_in; (void)out_size;
  const float* unity_in = (const float*)d_in[0];
  const float* cls_emb  = (const float*)d_in[1];
  const float* pad_emb  = (const float*)d_in[2];
  const float* pos_tab  = (const float*)d_in[3];
  const float* qkv_w    = (const float*)d_in[4];
  const float* qkv_b    = (const float*)d_in[5];
  const float* out_w    = (const float*)d_in[6];
  const float* out_b    = (const float*)d_in[7];
  const float* ln1_g    = (const float*)d_in[8];
  const float* ln1_b    = (const float*)d_in[9];
  const float* ln2_g    = (const float*)d_in[10];
  const float* ln2_b    = (const float*)d_in[11];
  const float* ff1_w    = (const float*)d_in[12];
  const float* ff1_b    = (const float*)d_in[13];
  const float* ff2_w    = (const float*)d_in[14];
  const float* ff2_b    = (const float*)d_in[15];
  const int* xid   = (const int*)d_in[16];
  const int* vmask = (const int*)d_in[17];
  const int* xpos  = (const int*)d_in[18];
  const int* hid   = (const int*)d_in[19];
  const int* hmask = (const int*)d_in[20];
  const int* subg  = (const int*)d_in[21];
  const int* pred  = (const int*)d_in[22];

  const i64 unity_b = (i64)NTOTAL * 256 * 4;
  const i64 ext_b   = (i64)(NHEDGE + 2) * 256 * 2;
  const int nq = 2 * 768 * 256, no = 2 * 256 * 256,
            n1 = 2 * 1024 * 256, n2 = 2 * 256 * 1024;
  const i64 wts_b = (i64)(nq + no + n1 + n2) * 2;
  const i64 idx_b = ((i64)NNODE + NHEDGE + 512 +
                     (NNODE + 1) + (NHEDGE + 1) +
                     (i64)NNODE * SE + (i64)NHEDGE * SV) * 4;
  const i64 per_elem = (i64)SE * (512 + 2048 + 512);
  int CHUNK = 8192;
  while (CHUNK > 256 &&
         unity_b + ext_b + wts_b + idx_b + (i64)CHUNK * per_elem > (i64)ws_size)
    CHUNK >>= 1;

  char* w = (char*)d_ws;
  float*  unity = (float*)w;  w += unity_b;
  ushort* ext   = (ushort*)w; w += ext_b;
  ushort* wq    = (ushort*)w; w += (i64)nq * 2;
  ushort* wo    = (ushort*)w; w += (i64)no * 2;
  ushort* w1    = (ushort*)w; w += (i64)n1 * 2;
  ushort* w2    = (ushort*)w; w += (i64)n2 * 2;
  ushort* X     = (ushort*)w; w += (i64)CHUNK * SE * 256 * 2;
  ushort* Y     = (ushort*)w; w += (i64)CHUNK * SE * 1024 * 2;
  ushort* O     = (ushort*)w; w += (i64)CHUNK * SE * 256 * 2;
  int* cntE  = (int*)w; w += (i64)NNODE * 4;
  int* cntV  = (int*)w; w += (i64)NHEDGE * 4;
  int* partE = (int*)w; w += 256 * 4;
  int* partV = (int*)w; w += 256 * 4;
  int* ssE   = (int*)w; w += (i64)(NNODE + 1) * 4;
  int* ssV   = (int*)w; w += (i64)(NHEDGE + 1) * 4;
  int* tokE  = (int*)w; w += (i64)NNODE * SE * 4;
  int* tokV  = (int*)w; w += (i64)NHEDGE * SV * 4;
  ushort* Ocls = O;
  ushort* Qcls = O + (i64)CHUNK * 256;
  ushort* X2   = O + (i64)2 * CHUNK * 256;
  ushort* X3   = O + (i64)3 * CHUNK * 256;

  f2b_cvt_k<<<512, 256, 0, stream>>>(qkv_w, wq, nq);
  f2b_cvt_k<<<512, 256, 0, stream>>>(out_w, wo, no);
  f2b_cvt_k<<<512, 256, 0, stream>>>(ff1_w, w1, n1);
  f2b_cvt_k<<<512, 256, 0, stream>>>(ff2_w, w2, n2);
  hipMemcpyAsync(unity, unity_in, unity_b, hipMemcpyDeviceToDevice, stream);
  ext_init_k<<<1, 256, 0, stream>>>(ext, pad_emb, cls_emb);

  cnt_k<<<NHEDGE / 256, 256, 0, stream>>>(vmask, ARITY, 1, cntV, NHEDGE);
  scan1_k<<<NHEDGE / 256, 256, 0, stream>>>(cntV, ssV, partV, NHEDGE);
  scan2_k<<<1, 256, 0, stream>>>(partV, NHEDGE / 256, ssV, NHEDGE);
  scan3_k<<<NHEDGE / 256, 256, 0, stream>>>(ssV, partV, vmask, ARITY, 1, tokV, NHEDGE);
  cnt_k<<<NNODE / 256, 256, 0, stream>>>(hmask, SE, 0, cntE, NNODE);
  scan1_k<<<NNODE / 256, 256, 0, stream>>>(cntE, ssE, partE, NNODE);
  scan2_k<<<1, 256, 0, stream>>>(partE, NNODE / 256, ssE, NNODE);
  scan3_k<<<NNODE / 256, 256, 0, stream>>>(ssE, partE, hmask, SE, 0, tokE, NNODE);

  for (int k = 0; k <= 2; k++) {
    // ---- V2E ----
    for (int c = 0; c < NHEDGE / CHUNK; c++) {
      const int e0 = c * CHUNK;
      const int* ssc = ssV + e0;
      const int Mmax = CHUNK * SV;
      gather_v2e_k<<<Mmax / 4, 256, 0, stream>>>(unity, pos_tab, xid, xpos,
                                                 tokV, ssc, CHUNK, X);
      gemm256_k<256, 1><<<dim3(3, Mmax / 256), 512, 0, stream>>>(
          X, wq, qkv_b, Y, Mmax, 768, ssc, CHUNK);
      attn1_k<SV><<<CHUNK, 16 * SV, 0, stream>>>(Y, ssc, O);
      gemm_ln_k<256><<<Mmax / 128, 512, 0, stream>>>(
          O, wo, out_b, X, 256, ln1_g, ln1_b, X, 256, Mmax, ssc, CHUNK, nullptr);
      gemm256_k<256, 2><<<dim3(4, Mmax / 256), 512, 0, stream>>>(
          X, w1, ff1_b, Y, Mmax, 1024, ssc, CHUNK);
      gemm_ln_k<1024><<<Mmax / 128, 512, 0, stream>>>(
          Y, w2, ff2_b, X, 256, ln2_g, ln2_b, X, 256, Mmax, ssc, CHUNK, nullptr);
      gemm256_k<256, 1><<<dim3(2, Mmax / 256), 512, 0, stream>>>(
          X, wq + (i64)768 * 256 + (i64)256 * 256, qkv_b + 768 + 256,
          Y, Mmax, 512, ssc, CHUNK);
      gemm_bf16_k<256, 1><<<dim3(2, CHUNK / 128), 256, 0, stream>>>(
          X, wq + (i64)768 * 256, qkv_b + 768, Qcls, CHUNK, 256,
          nullptr, 0, ssc);
      attn_cls_k<SV><<<CHUNK / 16, 256, 0, stream>>>(Qcls, Y, ssc, Ocls);
      gemm_ln_k<256><<<CHUNK / 128, 512, 0, stream>>>(
          Ocls, wo + (i64)256 * 256, out_b + 256, X, 256,
          ln1_g + 256, ln1_b + 256, X2, 256, CHUNK, nullptr, 0, ssc);
      gemm256_k<256, 2><<<dim3(4, CHUNK / 256), 512, 0, stream>>>(
          X2, w1 + (i64)1024 * 256, ff1_b + 1024, Y, CHUNK, 1024, nullptr, 0);
      gemm_ln_k<1024><<<CHUNK / 128, 512, 0, stream>>>(
          Y, w2 + (i64)256 * 1024, ff2_b + 256, X2, 256,
          ln2_g + 256, ln2_b + 256, ext + (i64)e0 * 256, 256, CHUNK,
          nullptr, 0, nullptr);
    }
    // ---- E2V ----
    if (k < 2) {
      for (int c = 0; c < NNODE / CHUNK; c++) {
        const int n0 = c * CHUNK;
        const int* ssc = ssE + n0;
        const int Mmax = CHUNK * SE;
        gather_e2v_k<<<Mmax / 4, 256, 0, stream>>>(ext, hid, tokE, ssc, CHUNK, X);
        gemm256_k<256, 1><<<dim3(3, Mmax / 256), 512, 0, stream>>>(
            X, wq, qkv_b, Y, Mmax, 768, ssc, CHUNK);
        attn1_k<SE><<<CHUNK, 16 * SE, 0, stream>>>(Y, ssc, O);
        gemm_ln_k<256><<<Mmax / 128, 512, 0, stream>>>(
            O, wo, out_b, X, 256, ln1_g, ln1_b, X, 256, Mmax, ssc, CHUNK, nullptr);
        gemm256_k<256, 2><<<dim3(4, Mmax / 256), 512, 0, stream>>>(
            X, w1, ff1_b, Y, Mmax, 1024, ssc, CHUNK);
        gemm_ln_k<1024><<<Mmax / 128, 512, 0, stream>>>(
            Y, w2, ff2_b, X, 256, ln2_g, ln2_b, X, 256, Mmax, ssc, CHUNK, nullptr);
        gemm256_k<256, 1><<<dim3(2, Mmax / 256), 512, 0, stream>>>(
            X, wq + (i64)768 * 256 + (i64)256 * 256, qkv_b + 768 + 256,
            Y, Mmax, 512, ssc, CHUNK);
        gemm_bf16_k<256, 1><<<dim3(2, CHUNK / 128), 256, 0, stream>>>(
            X, wq + (i64)768 * 256, qkv_b + 768, Qcls, CHUNK, 256,
            nullptr, 0, ssc);
        attn_cls_k<SE><<<CHUNK / 16, 256, 0, stream>>>(Qcls, Y, ssc, Ocls);
        gemm_ln_k<256><<<CHUNK / 128, 512, 0, stream>>>(
            Ocls, wo + (i64)256 * 256, out_b + 256, X, 256,
            ln1_g + 256, ln1_b + 256, X2, 256, CHUNK, nullptr, 0, ssc);
        gemm256_k<256, 2><<<dim3(4, CHUNK / 256), 512, 0, stream>>>(
            X2, w1 + (i64)1024 * 256, ff1_b + 1024, Y, CHUNK, 1024, nullptr, 0);
        gemm_ln_k<1024><<<CHUNK / 128, 512, 0, stream>>>(
            Y, w2 + (i64)256 * 1024, ff2_b + 256, X2, 256,
            ln2_g + 256, ln2_b + 256, X3, 256, CHUNK, nullptr, 0, nullptr);
        scatter_k<<<CHUNK / 4, 256, 0, stream>>>(X3, subg, unity, n0);
      }
    }
  }
  out_gather_k<<<64, 256, 0, stream>>>(ext, pred, (float*)d_out);
}